// Round 1
// baseline (200.881 us; speedup 1.0000x reference)
//
#include <hip/hip_runtime.h>
#include <hip/hip_bf16.h>
#include <math.h>

// ArcFace loss, MI355X. B=2048 samples, D=512 feat, C=32768 classes.
// Strategy: fp32 row-normalize -> bf16; 128x128 MFMA GEMM (16x16x32 bf16)
// with fused exp(64*logit) row-sum epilogue (logits never materialized);
// target logit computed separately in fp32 for numerator accuracy.

#define BN 2048
#define DK 512
#define CN 32768

typedef __attribute__((ext_vector_type(8))) short short8;
typedef __attribute__((ext_vector_type(4))) float floatx4;

__device__ inline float dot4(floatx4 a, floatx4 b) {
  return a.x * b.x + a.y * b.y + a.z * b.z + a.w * b.w;
}

__device__ inline unsigned short f2bf(float f) {
  union { float f; unsigned u; } a; a.f = f;
  unsigned u = a.u;
  return (unsigned short)((u + 0x7fffu + ((u >> 16) & 1u)) >> 16);  // RNE
}

__device__ inline uint2 pack4(floatx4 v) {
  uint2 r;
  r.x = (unsigned)f2bf(v.x) | ((unsigned)f2bf(v.y) << 16);
  r.y = (unsigned)f2bf(v.z) | ((unsigned)f2bf(v.w) << 16);
  return r;
}

__device__ inline void async_ld16(const void* g, void* l) {
  // per-lane 16B global -> LDS at (wave-uniform base + lane*16)
  __builtin_amdgcn_global_load_lds(
      (const __attribute__((address_space(1))) void*)g,
      (__attribute__((address_space(3))) void*)l, 16, 0, 0);
}

// ---- kernel 1: normalize features; emit fp32 (for tgt) and bf16 (for GEMM)
__global__ void feat_norm_kernel(const float* __restrict__ feat,
                                 float* __restrict__ fnorm,
                                 __hip_bfloat16* __restrict__ fb) {
  const int row = blockIdx.x;
  const int l = threadIdx.x;  // 0..63, one wave
  const floatx4* src = (const floatx4*)(feat + (size_t)row * DK);
  floatx4 v0 = src[l];
  floatx4 v1 = src[64 + l];
  float s = dot4(v0, v0) + dot4(v1, v1);
#pragma unroll
  for (int off = 1; off < 64; off <<= 1) s += __shfl_xor(s, off, 64);
  const float scale = 1.0f / fmaxf(sqrtf(s), 1e-12f);
  v0 *= scale; v1 *= scale;
  floatx4* dst = (floatx4*)(fnorm + (size_t)row * DK);
  dst[l] = v0; dst[64 + l] = v1;
  uint2* db = (uint2*)(fb + (size_t)row * DK);
  db[l] = pack4(v0);
  db[64 + l] = pack4(v1);
}

// ---- kernel 2: normalize weights -> bf16 (4 rows per 256-thread block)
__global__ void weight_norm_kernel(const float* __restrict__ w,
                                   __hip_bfloat16* __restrict__ wb) {
  const int row = blockIdx.x * 4 + (threadIdx.x >> 6);
  const int l = threadIdx.x & 63;
  const floatx4* src = (const floatx4*)(w + (size_t)row * DK);
  floatx4 v0 = src[l];
  floatx4 v1 = src[64 + l];
  float s = dot4(v0, v0) + dot4(v1, v1);
#pragma unroll
  for (int off = 1; off < 64; off <<= 1) s += __shfl_xor(s, off, 64);
  const float scale = 1.0f / fmaxf(sqrtf(s), 1e-12f);
  v0 *= scale; v1 *= scale;
  uint2* db = (uint2*)(wb + (size_t)row * DK);
  db[l] = pack4(v0);
  db[64 + l] = pack4(v1);
}

// ---- kernel 3: fp32 target logit tgt[i] = <fnorm[i], w[y[i]]/||w[y[i]]||>
__global__ void tgt_kernel(const float* __restrict__ fnorm,
                           const int* __restrict__ y,
                           const float* __restrict__ w,
                           float* __restrict__ tgt) {
  const int i = blockIdx.x;
  const int l = threadIdx.x;  // one wave
  const int cls = y[i];
  const floatx4* fr = (const floatx4*)(fnorm + (size_t)i * DK);
  const floatx4* wr = (const floatx4*)(w + (size_t)cls * DK);
  floatx4 f0 = fr[l], f1 = fr[64 + l];
  floatx4 w0 = wr[l], w1 = wr[64 + l];
  float d = dot4(f0, w0) + dot4(f1, w1);
  float s = dot4(w0, w0) + dot4(w1, w1);
#pragma unroll
  for (int off = 1; off < 64; off <<= 1) {
    d += __shfl_xor(d, off, 64);
    s += __shfl_xor(s, off, 64);
  }
  if (l == 0) tgt[i] = d / fmaxf(sqrtf(s), 1e-12f);
}

// ---- kernel 4: 128x128 bf16 MFMA GEMM + fused exp row-sum
// grid (BN/128, CN/128): x = M-tile (fast) so 16 consecutive blocks share
// one 128KB weight tile in L2. 256 thr = 4 waves, each wave a 64x64 subtile.
__launch_bounds__(256, 2)
__global__ void gemm_exp_kernel(const __hip_bfloat16* __restrict__ fb,   // [BN, DK]
                                const __hip_bfloat16* __restrict__ wb,   // [CN, DK]
                                float* __restrict__ rowsum) {
  __shared__ short As[128 * 32];   // 8 KB, row-major 128x32, NO padding (global_load_lds)
  __shared__ short Bs[128 * 32];   // 8 KB
  __shared__ float lsum[128];

  const int tid  = threadIdx.x;
  const int wave = tid >> 6;
  const int lane = tid & 63;
  const int tileM = blockIdx.x * 128;
  const int tileN = blockIdx.y * 128;

  const int wm = (wave >> 1) * 64;  // wave's M offset in tile
  const int wn = (wave & 1) * 64;   // wave's N offset in tile

  floatx4 acc[4][4];
#pragma unroll
  for (int mi = 0; mi < 4; ++mi)
#pragma unroll
    for (int ni = 0; ni < 4; ++ni)
      acc[mi][ni] = (floatx4){0.f, 0.f, 0.f, 0.f};

  // staging: each wave stages 32 rows of A and 32 rows of B (2 insts each)
  const int rA = lane >> 2;   // 0..15 row within 16-row chunk
  const int cA = lane & 3;    // 0..3  -> 8 shorts (16B) each
  const char* gA = (const char*)fb + ((size_t)(tileM + wave * 32 + rA) * DK + cA * 8) * 2;
  const char* gB = (const char*)wb + ((size_t)(tileN + wave * 32 + rA) * DK + cA * 8) * 2;
  short* lA = &As[(wave * 32) * 32];  // wave-uniform LDS base
  short* lB = &Bs[(wave * 32) * 32];

  const int mrow = lane & 15;        // fragment row (M or N index)
  const int kq   = (lane >> 4) * 8;  // fragment k offset

  for (int kk = 0; kk < DK / 32; ++kk) {
    __syncthreads();  // prior iter's LDS reads complete
    async_ld16(gA,                 lA);
    async_ld16(gA + 16 * DK * 2,   lA + 16 * 32);
    async_ld16(gB,                 lB);
    async_ld16(gB + 16 * DK * 2,   lB + 16 * 32);
    gA += 32 * 2;
    gB += 32 * 2;
    __syncthreads();  // drains vmcnt(0): tiles resident

    short8 af[4], bf[4];
#pragma unroll
    for (int mi = 0; mi < 4; ++mi)
      af[mi] = *(const short8*)&As[(wm + mi * 16 + mrow) * 32 + kq];
#pragma unroll
    for (int ni = 0; ni < 4; ++ni)
      bf[ni] = *(const short8*)&Bs[(wn + ni * 16 + mrow) * 32 + kq];
#pragma unroll
    for (int mi = 0; mi < 4; ++mi)
#pragma unroll
      for (int ni = 0; ni < 4; ++ni)
        acc[mi][ni] = __builtin_amdgcn_mfma_f32_16x16x32_bf16(
            af[mi], bf[ni], acc[mi][ni], 0, 0, 0);
  }

  // epilogue: v = sum_n exp(64 * wf) per row, accumulated via LDS then global
  __syncthreads();
  if (tid < 128) lsum[tid] = 0.0f;
  __syncthreads();

  const int rowq = (lane >> 4) * 4;  // C/D layout: row = quad*4 + reg
#pragma unroll
  for (int mi = 0; mi < 4; ++mi) {
#pragma unroll
    for (int r = 0; r < 4; ++r) {
      float v = 0.f;
#pragma unroll
      for (int ni = 0; ni < 4; ++ni)
        v += __expf(64.0f * acc[mi][ni][r]);
      // reduce across the 16 lanes holding cols 0..15 (same row)
      v += __shfl_xor(v, 1, 64);
      v += __shfl_xor(v, 2, 64);
      v += __shfl_xor(v, 4, 64);
      v += __shfl_xor(v, 8, 64);
      if ((lane & 15) == 0)
        atomicAdd(&lsum[wm + mi * 16 + rowq + r], v);
    }
  }
  __syncthreads();
  if (tid < 128)
    atomicAdd(&rowsum[tileM + tid], lsum[tid]);
}

// ---- kernel 5: final loss
__global__ void loss_kernel(const float* __restrict__ tgt,
                            const float* __restrict__ rowsum,
                            float* __restrict__ out) {
  __shared__ float wsum[4];
  const int t = threadIdx.x;
  float sum = 0.f;
  const float cM = 0.87758256189037271f;  // cos(0.5)
  const float sM = 0.47942553860420301f;  // sin(0.5)
  for (int i = t; i < BN; i += 256) {
    const float tg_raw = tgt[i];
    const float tg = fminf(fmaxf(tg_raw, -1.f + 1e-7f), 1.f - 1e-7f);
    const float num = 64.f * (tg * cM - sqrtf(fmaxf(1.f - tg * tg, 0.f)) * sM);
    const float den = expf(num) + rowsum[i] - expf(64.f * tg_raw);
    sum += num - logf(den);
  }
#pragma unroll
  for (int off = 1; off < 64; off <<= 1) sum += __shfl_xor(sum, off, 64);
  if ((t & 63) == 0) wsum[t >> 6] = sum;
  __syncthreads();
  if (t == 0)
    out[0] = -(wsum[0] + wsum[1] + wsum[2] + wsum[3]) * (1.0f / (float)BN);
}

extern "C" void kernel_launch(void* const* d_in, const int* in_sizes, int n_in,
                              void* d_out, int out_size, void* d_ws, size_t ws_size,
                              hipStream_t stream) {
  const float* features = (const float*)d_in[0];
  const int*   y_true   = (const int*)d_in[1];
  const float* weight   = (const float*)d_in[2];
  float* out = (float*)d_out;

  char* ws = (char*)d_ws;
  __hip_bfloat16* wb    = (__hip_bfloat16*)(ws);                 // 32 MB
  __hip_bfloat16* fb    = (__hip_bfloat16*)(ws + 33554432);      //  2 MB
  float* fnorm          = (float*)(ws + 35651584);               //  4 MB
  float* tgt            = (float*)(ws + 39845888);               //  8 KB
  float* rowsum         = (float*)(ws + 39854080);               //  8 KB

  hipMemsetAsync(rowsum, 0, BN * sizeof(float), stream);

  feat_norm_kernel<<<BN, 64, 0, stream>>>(features, fnorm, fb);
  weight_norm_kernel<<<CN / 4, 256, 0, stream>>>(weight, wb);
  tgt_kernel<<<BN, 64, 0, stream>>>(fnorm, y_true, weight, tgt);
  gemm_exp_kernel<<<dim3(BN / 128, CN / 128), 256, 0, stream>>>(fb, wb, rowsum);
  loss_kernel<<<1, 256, 0, stream>>>(tgt, rowsum, out);
}

// Round 2
// 191.910 us; speedup vs baseline: 1.0467x; 1.0467x over previous
//
#include <hip/hip_runtime.h>
#include <hip/hip_bf16.h>
#include <math.h>

// ArcFace loss, MI355X. B=2048, D=512, C=32768.
// R2: (a) XOR-swizzled LDS (16B chunks, chunk^=(row>>1)&3) kills the 8-way
// bank conflict on ds_read_b128 (R1: 8.4M conflict cycles = +4 cyc/read);
// (b) tgt gather fused into feat_norm, rowsum init fused too (6->4 dispatches).

#define BN 2048
#define DK 512
#define CN 32768

typedef __attribute__((ext_vector_type(8))) short short8;
typedef __attribute__((ext_vector_type(4))) float floatx4;

__device__ inline float dot4(floatx4 a, floatx4 b) {
  return a.x * b.x + a.y * b.y + a.z * b.z + a.w * b.w;
}

__device__ inline unsigned short f2bf(float f) {
  union { float f; unsigned u; } a; a.f = f;
  unsigned u = a.u;
  return (unsigned short)((u + 0x7fffu + ((u >> 16) & 1u)) >> 16);  // RNE
}

__device__ inline uint2 pack4(floatx4 v) {
  uint2 r;
  r.x = (unsigned)f2bf(v.x) | ((unsigned)f2bf(v.y) << 16);
  r.y = (unsigned)f2bf(v.z) | ((unsigned)f2bf(v.w) << 16);
  return r;
}

__device__ inline void async_ld16(const void* g, void* l) {
  // per-lane 16B global -> LDS at (wave-uniform base + lane*16)
  __builtin_amdgcn_global_load_lds(
      (const __attribute__((address_space(1))) void*)g,
      (__attribute__((address_space(3))) void*)l, 16, 0, 0);
}

// ---- kernel 1: normalize features -> bf16; fused fp32 target logit + rowsum init
__global__ void feat_tgt_kernel(const float* __restrict__ feat,
                                const int* __restrict__ y,
                                const float* __restrict__ w,
                                __hip_bfloat16* __restrict__ fb,
                                float* __restrict__ tgt,
                                float* __restrict__ rowsum) {
  const int i = blockIdx.x;
  const int l = threadIdx.x;  // one wave
  const floatx4* src = (const floatx4*)(feat + (size_t)i * DK);
  floatx4 v0 = src[l];
  floatx4 v1 = src[64 + l];
  const int cls = y[i];
  const floatx4* wr = (const floatx4*)(w + (size_t)cls * DK);
  floatx4 w0 = wr[l], w1 = wr[64 + l];

  float s  = dot4(v0, v0) + dot4(v1, v1);
  float d  = dot4(v0, w0) + dot4(v1, w1);
  float wn = dot4(w0, w0) + dot4(w1, w1);
#pragma unroll
  for (int off = 1; off < 64; off <<= 1) {
    s  += __shfl_xor(s, off, 64);
    d  += __shfl_xor(d, off, 64);
    wn += __shfl_xor(wn, off, 64);
  }
  const float fscale = 1.0f / fmaxf(sqrtf(s), 1e-12f);
  v0 *= fscale; v1 *= fscale;
  uint2* db = (uint2*)(fb + (size_t)i * DK);
  db[l] = pack4(v0);
  db[64 + l] = pack4(v1);
  if (l == 0) {
    tgt[i] = d * fscale / fmaxf(sqrtf(wn), 1e-12f);
    rowsum[i] = 0.0f;
  }
}

// ---- kernel 2: normalize weights -> bf16 (4 rows per 256-thread block)
__global__ void weight_norm_kernel(const float* __restrict__ w,
                                   __hip_bfloat16* __restrict__ wb) {
  const int row = blockIdx.x * 4 + (threadIdx.x >> 6);
  const int l = threadIdx.x & 63;
  const floatx4* src = (const floatx4*)(w + (size_t)row * DK);
  floatx4 v0 = src[l];
  floatx4 v1 = src[64 + l];
  float s = dot4(v0, v0) + dot4(v1, v1);
#pragma unroll
  for (int off = 1; off < 64; off <<= 1) s += __shfl_xor(s, off, 64);
  const float scale = 1.0f / fmaxf(sqrtf(s), 1e-12f);
  v0 *= scale; v1 *= scale;
  uint2* db = (uint2*)(wb + (size_t)row * DK);
  db[l] = pack4(v0);
  db[64 + l] = pack4(v1);
}

// ---- kernel 3: 128x128 bf16 MFMA GEMM + fused exp row-sum
// LDS layout: row-major 128x32 shorts, but each row's four 16B chunks are
// XOR-permuted: chunk_stored = chunk_logical ^ ((row>>1)&3). This spreads the
// 16 fragment-read lanes (rows base..base+15, same k-chunk) over all 8
// bank-quads -> 2 lanes/quad (free) instead of 8-way conflict.
__launch_bounds__(256, 2)
__global__ void gemm_exp_kernel(const __hip_bfloat16* __restrict__ fb,   // [BN, DK]
                                const __hip_bfloat16* __restrict__ wb,   // [CN, DK]
                                float* __restrict__ rowsum) {
  __shared__ short As[128 * 32];   // 8 KB
  __shared__ short Bs[128 * 32];   // 8 KB
  __shared__ float lsum[128];

  const int tid  = threadIdx.x;
  const int wave = tid >> 6;
  const int lane = tid & 63;
  const int tileM = blockIdx.x * 128;
  const int tileN = blockIdx.y * 128;

  const int wm = (wave >> 1) * 64;  // wave's M offset in tile
  const int wn = (wave & 1) * 64;   // wave's N offset in tile

  floatx4 acc[4][4];
#pragma unroll
  for (int mi = 0; mi < 4; ++mi)
#pragma unroll
    for (int ni = 0; ni < 4; ++ni)
      acc[mi][ni] = (floatx4){0.f, 0.f, 0.f, 0.f};

  // staging: lane l writes LDS row wave*32+(l>>2) (+16 for 2nd inst), chunk l&3.
  // It must therefore FETCH global chunk (l&3) ^ swz(row).
  const int rA = lane >> 2;
  const int cA = lane & 3;
  const int r0 = wave * 32 + rA;
  const int r1 = r0 + 16;
  const int g0 = cA ^ ((r0 >> 1) & 3);
  const int g1 = cA ^ ((r1 >> 1) & 3);
  const char* gA0 = (const char*)fb + ((size_t)(tileM + r0) * DK + g0 * 8) * 2;
  const char* gA1 = (const char*)fb + ((size_t)(tileM + r1) * DK + g1 * 8) * 2;
  const char* gB0 = (const char*)wb + ((size_t)(tileN + r0) * DK + g0 * 8) * 2;
  const char* gB1 = (const char*)wb + ((size_t)(tileN + r1) * DK + g1 * 8) * 2;
  short* lA = &As[(wave * 32) * 32];  // wave-uniform LDS base
  short* lB = &Bs[(wave * 32) * 32];

  const int mrow = lane & 15;   // fragment row (M or N index within 16)
  const int gk   = lane >> 4;   // logical k-chunk (16B) wanted by this lane

  for (int kk = 0; kk < DK / 32; ++kk) {
    __syncthreads();  // prior iter's LDS reads complete
    async_ld16(gA0, lA);
    async_ld16(gA1, lA + 16 * 32);
    async_ld16(gB0, lB);
    async_ld16(gB1, lB + 16 * 32);
    gA0 += 64; gA1 += 64; gB0 += 64; gB1 += 64;
    __syncthreads();  // drains vmcnt(0): tiles resident

    short8 af[4], bf[4];
#pragma unroll
    for (int mi = 0; mi < 4; ++mi) {
      const int row = wm + mi * 16 + mrow;
      const int c = gk ^ ((row >> 1) & 3);
      af[mi] = *(const short8*)&As[row * 32 + c * 8];
    }
#pragma unroll
    for (int ni = 0; ni < 4; ++ni) {
      const int row = wn + ni * 16 + mrow;
      const int c = gk ^ ((row >> 1) & 3);
      bf[ni] = *(const short8*)&Bs[row * 32 + c * 8];
    }
#pragma unroll
    for (int mi = 0; mi < 4; ++mi)
#pragma unroll
      for (int ni = 0; ni < 4; ++ni)
        acc[mi][ni] = __builtin_amdgcn_mfma_f32_16x16x32_bf16(
            af[mi], bf[ni], acc[mi][ni], 0, 0, 0);
  }

  // epilogue: rowsum[m] += sum_n exp(64 * wf[m][n])
  __syncthreads();
  if (tid < 128) lsum[tid] = 0.0f;
  __syncthreads();

  const int rowq = (lane >> 4) * 4;  // C/D layout: row = quad*4 + reg
#pragma unroll
  for (int mi = 0; mi < 4; ++mi) {
#pragma unroll
    for (int r = 0; r < 4; ++r) {
      float v = 0.f;
#pragma unroll
      for (int ni = 0; ni < 4; ++ni)
        v += __expf(64.0f * acc[mi][ni][r]);
      v += __shfl_xor(v, 1, 64);
      v += __shfl_xor(v, 2, 64);
      v += __shfl_xor(v, 4, 64);
      v += __shfl_xor(v, 8, 64);
      if ((lane & 15) == 0)
        atomicAdd(&lsum[wm + mi * 16 + rowq + r], v);
    }
  }
  __syncthreads();
  if (tid < 128)
    atomicAdd(&rowsum[tileM + tid], lsum[tid]);
}

// ---- kernel 4: final loss
__global__ void loss_kernel(const float* __restrict__ tgt,
                            const float* __restrict__ rowsum,
                            float* __restrict__ out) {
  __shared__ float wsum[4];
  const int t = threadIdx.x;
  float sum = 0.f;
  const float cM = 0.87758256189037271f;  // cos(0.5)
  const float sM = 0.47942553860420301f;  // sin(0.5)
  for (int i = t; i < BN; i += 256) {
    const float tg_raw = tgt[i];
    const float tg = fminf(fmaxf(tg_raw, -1.f + 1e-7f), 1.f - 1e-7f);
    const float num = 64.f * (tg * cM - sqrtf(fmaxf(1.f - tg * tg, 0.f)) * sM);
    const float den = expf(num) + rowsum[i] - expf(64.f * tg_raw);
    sum += num - logf(den);
  }
#pragma unroll
  for (int off = 1; off < 64; off <<= 1) sum += __shfl_xor(sum, off, 64);
  if ((t & 63) == 0) wsum[t >> 6] = sum;
  __syncthreads();
  if (t == 0)
    out[0] = -(wsum[0] + wsum[1] + wsum[2] + wsum[3]) * (1.0f / (float)BN);
}

extern "C" void kernel_launch(void* const* d_in, const int* in_sizes, int n_in,
                              void* d_out, int out_size, void* d_ws, size_t ws_size,
                              hipStream_t stream) {
  const float* features = (const float*)d_in[0];
  const int*   y_true   = (const int*)d_in[1];
  const float* weight   = (const float*)d_in[2];
  float* out = (float*)d_out;

  char* ws = (char*)d_ws;
  __hip_bfloat16* wb = (__hip_bfloat16*)(ws);             // 32 MB
  __hip_bfloat16* fb = (__hip_bfloat16*)(ws + 33554432);  //  2 MB
  float* tgt         = (float*)(ws + 35651584);           //  8 KB
  float* rowsum      = (float*)(ws + 35659776);           //  8 KB

  feat_tgt_kernel<<<BN, 64, 0, stream>>>(features, y_true, weight, fb, tgt, rowsum);
  weight_norm_kernel<<<CN / 4, 256, 0, stream>>>(weight, wb);
  gemm_exp_kernel<<<dim3(BN / 128, CN / 128), 256, 0, stream>>>(fb, wb, rowsum);
  loss_kernel<<<1, 256, 0, stream>>>(tgt, rowsum, out);
}

// Round 3
// 186.726 us; speedup vs baseline: 1.0758x; 1.0278x over previous
//
#include <hip/hip_runtime.h>
#include <hip/hip_bf16.h>
#include <math.h>

// ArcFace loss, MI355X. B=2048, D=512, C=32768.
// R3: 128x256 GEMM tile, 512 thr / 8 waves (doubles MFMA per barrier-phase,
// halves epilogue count, raises occupancy ceiling to 32 waves/CU); prep
// kernels fused into one dispatch. XOR-swizzled LDS kept (R2: conflicts=0).

#define BN 2048
#define DK 512
#define CN 32768

typedef __attribute__((ext_vector_type(8))) short short8;
typedef __attribute__((ext_vector_type(4))) float floatx4;

__device__ inline float dot4(floatx4 a, floatx4 b) {
  return a.x * b.x + a.y * b.y + a.z * b.z + a.w * b.w;
}

__device__ inline unsigned short f2bf(float f) {
  union { float f; unsigned u; } a; a.f = f;
  unsigned u = a.u;
  return (unsigned short)((u + 0x7fffu + ((u >> 16) & 1u)) >> 16);  // RNE
}

__device__ inline uint2 pack4(floatx4 v) {
  uint2 r;
  r.x = (unsigned)f2bf(v.x) | ((unsigned)f2bf(v.y) << 16);
  r.y = (unsigned)f2bf(v.z) | ((unsigned)f2bf(v.w) << 16);
  return r;
}

__device__ inline void async_ld16(const void* g, void* l) {
  // per-lane 16B global -> LDS at (wave-uniform base + lane*16)
  __builtin_amdgcn_global_load_lds(
      (const __attribute__((address_space(1))) void*)g,
      (__attribute__((address_space(3))) void*)l, 16, 0, 0);
}

// ---- kernel 1: fused prep.
// blocks [0, 8192): weight rows -> normalized bf16 wb (4 rows/block)
// blocks [8192, 8704): features -> normalized bf16 fb + fp32 tgt + rowsum=0
__global__ void prep_kernel(const float* __restrict__ feat,
                            const int* __restrict__ y,
                            const float* __restrict__ w,
                            __hip_bfloat16* __restrict__ fb,
                            __hip_bfloat16* __restrict__ wb,
                            float* __restrict__ tgt,
                            float* __restrict__ rowsum) {
  const int wave = threadIdx.x >> 6;
  const int l = threadIdx.x & 63;
  if (blockIdx.x < 8192) {
    const int row = blockIdx.x * 4 + wave;
    const floatx4* src = (const floatx4*)(w + (size_t)row * DK);
    floatx4 v0 = src[l];
    floatx4 v1 = src[64 + l];
    float s = dot4(v0, v0) + dot4(v1, v1);
#pragma unroll
    for (int off = 1; off < 64; off <<= 1) s += __shfl_xor(s, off, 64);
    const float scale = 1.0f / fmaxf(sqrtf(s), 1e-12f);
    v0 *= scale; v1 *= scale;
    uint2* db = (uint2*)(wb + (size_t)row * DK);
    db[l] = pack4(v0);
    db[64 + l] = pack4(v1);
  } else {
    const int i = (blockIdx.x - 8192) * 4 + wave;
    const floatx4* src = (const floatx4*)(feat + (size_t)i * DK);
    floatx4 v0 = src[l];
    floatx4 v1 = src[64 + l];
    const int cls = y[i];
    const floatx4* wr = (const floatx4*)(w + (size_t)cls * DK);
    floatx4 w0 = wr[l], w1 = wr[64 + l];
    float s  = dot4(v0, v0) + dot4(v1, v1);
    float d  = dot4(v0, w0) + dot4(v1, w1);
    float wn = dot4(w0, w0) + dot4(w1, w1);
#pragma unroll
    for (int off = 1; off < 64; off <<= 1) {
      s  += __shfl_xor(s, off, 64);
      d  += __shfl_xor(d, off, 64);
      wn += __shfl_xor(wn, off, 64);
    }
    const float fscale = 1.0f / fmaxf(sqrtf(s), 1e-12f);
    v0 *= fscale; v1 *= fscale;
    uint2* db = (uint2*)(fb + (size_t)i * DK);
    db[l] = pack4(v0);
    db[64 + l] = pack4(v1);
    if (l == 0) {
      tgt[i] = d * fscale / fmaxf(sqrtf(wn), 1e-12f);
      rowsum[i] = 0.0f;
    }
  }
}

// ---- kernel 2: 128(M)x256(N) bf16 MFMA GEMM + fused exp row-sum.
// 512 thr = 8 waves, each a 64x64 subtile (wm=(w>>2)*64, wn=(w&3)*64).
// LDS: As 128x32, Bs 256x32 shorts; 16B chunks XOR-swizzled by (row>>1)&3.
__launch_bounds__(512, 4)
__global__ void gemm_exp_kernel(const __hip_bfloat16* __restrict__ fb,   // [BN, DK]
                                const __hip_bfloat16* __restrict__ wb,   // [CN, DK]
                                float* __restrict__ rowsum) {
  __shared__ short As[128 * 32];   //  8 KB
  __shared__ short Bs[256 * 32];   // 16 KB
  __shared__ float lsum[128];

  const int tid  = threadIdx.x;
  const int wave = tid >> 6;
  const int lane = tid & 63;
  const int tileM = blockIdx.x * 128;
  const int tileN = blockIdx.y * 256;

  const int wm = (wave >> 2) * 64;  // wave M offset (0 or 64)
  const int wn = (wave & 3) * 64;   // wave N offset (0..192)

  if (tid < 128) lsum[tid] = 0.0f;  // covered by first K-loop barrier

  floatx4 acc[4][4];
#pragma unroll
  for (int mi = 0; mi < 4; ++mi)
#pragma unroll
    for (int ni = 0; ni < 4; ++ni)
      acc[mi][ni] = (floatx4){0.f, 0.f, 0.f, 0.f};

  // staging: 1536 16B chunks/iter (A:512, Blo:512, Bhi:512), 3 insts/thread.
  // chunk ch -> row ch>>2, stored col ch&3, fetched global col swizzled.
  const int sr = tid >> 2;                 // 0..127
  const int sc = tid & 3;
  const int sg = sc ^ ((sr >> 1) & 3);     // same for all three (row+128 preserves bits 1..2 of row>>1 mod 4)
  const char* gA  = (const char*)fb + ((size_t)(tileM + sr)       * DK + sg * 8) * 2;
  const char* gB0 = (const char*)wb + ((size_t)(tileN + sr)       * DK + sg * 8) * 2;
  const char* gB1 = (const char*)wb + ((size_t)(tileN + 128 + sr) * DK + sg * 8) * 2;
  short* lA  = &As[wave * 512];            // wave-uniform LDS bases
  short* lB0 = &Bs[wave * 512];
  short* lB1 = &Bs[4096 + wave * 512];

  const int mrow = lane & 15;   // fragment row (M or N index within 16)
  const int gk   = lane >> 4;   // logical k-chunk (16B) wanted by this lane

  for (int kk = 0; kk < DK / 32; ++kk) {
    __syncthreads();  // prior iter's LDS reads complete
    async_ld16(gA,  lA);
    async_ld16(gB0, lB0);
    async_ld16(gB1, lB1);
    gA += 64; gB0 += 64; gB1 += 64;
    __syncthreads();  // drains vmcnt(0): tiles resident

    short8 af[4], bf[4];
#pragma unroll
    for (int mi = 0; mi < 4; ++mi) {
      const int row = wm + mi * 16 + mrow;
      const int c = gk ^ ((row >> 1) & 3);
      af[mi] = *(const short8*)&As[row * 32 + c * 8];
    }
#pragma unroll
    for (int ni = 0; ni < 4; ++ni) {
      const int row = wn + ni * 16 + mrow;
      const int c = gk ^ ((row >> 1) & 3);
      bf[ni] = *(const short8*)&Bs[row * 32 + c * 8];
    }
#pragma unroll
    for (int mi = 0; mi < 4; ++mi)
#pragma unroll
      for (int ni = 0; ni < 4; ++ni)
        acc[mi][ni] = __builtin_amdgcn_mfma_f32_16x16x32_bf16(
            af[mi], bf[ni], acc[mi][ni], 0, 0, 0);
  }

  // epilogue: rowsum[m] += sum_n exp(64 * wf[m][n])
  const int rowq = (lane >> 4) * 4;  // C/D layout: row = quad*4 + reg
#pragma unroll
  for (int mi = 0; mi < 4; ++mi) {
#pragma unroll
    for (int r = 0; r < 4; ++r) {
      float v = 0.f;
#pragma unroll
      for (int ni = 0; ni < 4; ++ni)
        v += __expf(64.0f * acc[mi][ni][r]);
      v += __shfl_xor(v, 1, 64);
      v += __shfl_xor(v, 2, 64);
      v += __shfl_xor(v, 4, 64);
      v += __shfl_xor(v, 8, 64);
      if ((lane & 15) == 0)
        atomicAdd(&lsum[wm + mi * 16 + rowq + r], v);
    }
  }
  __syncthreads();
  if (tid < 128)
    atomicAdd(&rowsum[tileM + tid], lsum[tid]);
}

// ---- kernel 3: final loss
__global__ void loss_kernel(const float* __restrict__ tgt,
                            const float* __restrict__ rowsum,
                            float* __restrict__ out) {
  __shared__ float wsum[8];
  const int t = threadIdx.x;
  float sum = 0.f;
  const float cM = 0.87758256189037271f;  // cos(0.5)
  const float sM = 0.47942553860420301f;  // sin(0.5)
  for (int i = t; i < BN; i += 512) {
    const float tg_raw = tgt[i];
    const float tg = fminf(fmaxf(tg_raw, -1.f + 1e-7f), 1.f - 1e-7f);
    const float num = 64.f * (tg * cM - sqrtf(fmaxf(1.f - tg * tg, 0.f)) * sM);
    const float den = expf(num) + rowsum[i] - expf(64.f * tg_raw);
    sum += num - logf(den);
  }
#pragma unroll
  for (int off = 1; off < 64; off <<= 1) sum += __shfl_xor(sum, off, 64);
  if ((t & 63) == 0) wsum[t >> 6] = sum;
  __syncthreads();
  if (t == 0) {
    float tot = 0.f;
#pragma unroll
    for (int k = 0; k < 8; ++k) tot += wsum[k];
    out[0] = -tot * (1.0f / (float)BN);
  }
}

extern "C" void kernel_launch(void* const* d_in, const int* in_sizes, int n_in,
                              void* d_out, int out_size, void* d_ws, size_t ws_size,
                              hipStream_t stream) {
  const float* features = (const float*)d_in[0];
  const int*   y_true   = (const int*)d_in[1];
  const float* weight   = (const float*)d_in[2];
  float* out = (float*)d_out;

  char* ws = (char*)d_ws;
  __hip_bfloat16* wb = (__hip_bfloat16*)(ws);             // 32 MB
  __hip_bfloat16* fb = (__hip_bfloat16*)(ws + 33554432);  //  2 MB
  float* tgt         = (float*)(ws + 35651584);           //  8 KB
  float* rowsum      = (float*)(ws + 35659776);           //  8 KB

  prep_kernel<<<8192 + 512, 256, 0, stream>>>(features, y_true, weight,
                                              fb, wb, tgt, rowsum);
  gemm_exp_kernel<<<dim3(BN / 128, CN / 256), 512, 0, stream>>>(fb, wb, rowsum);
  loss_kernel<<<1, 512, 0, stream>>>(tgt, rowsum, out);
}

// Round 4
// 181.473 us; speedup vs baseline: 1.1069x; 1.0289x over previous
//
#include <hip/hip_runtime.h>
#include <hip/hip_bf16.h>
#include <math.h>

// ArcFace loss, MI355X. B=2048, D=512, C=32768.
// R4: ping-pong LDS double buffer in the GEMM K-loop, ONE barrier per iter:
// async global_load_lds for chunk k+1 issued right after the barrier, so the
// load is in flight across the whole MFMA phase instead of being drained by
// a vmcnt(0) barrier immediately after issue (R3: 45% stall, MfmaUtil 32%).
// 128x256 tile, 512 thr / 8 waves; XOR-swizzled LDS (conflicts=0 since R2).

#define BN 2048
#define DK 512
#define CN 32768

typedef __attribute__((ext_vector_type(8))) short short8;
typedef __attribute__((ext_vector_type(4))) float floatx4;

__device__ inline float dot4(floatx4 a, floatx4 b) {
  return a.x * b.x + a.y * b.y + a.z * b.z + a.w * b.w;
}

__device__ inline unsigned short f2bf(float f) {
  union { float f; unsigned u; } a; a.f = f;
  unsigned u = a.u;
  return (unsigned short)((u + 0x7fffu + ((u >> 16) & 1u)) >> 16);  // RNE
}

__device__ inline uint2 pack4(floatx4 v) {
  uint2 r;
  r.x = (unsigned)f2bf(v.x) | ((unsigned)f2bf(v.y) << 16);
  r.y = (unsigned)f2bf(v.z) | ((unsigned)f2bf(v.w) << 16);
  return r;
}

__device__ inline void async_ld16(const void* g, void* l) {
  // per-lane 16B global -> LDS at (wave-uniform base + lane*16)
  __builtin_amdgcn_global_load_lds(
      (const __attribute__((address_space(1))) void*)g,
      (__attribute__((address_space(3))) void*)l, 16, 0, 0);
}

// ---- kernel 1: fused prep.
// blocks [0, 8192): weight rows -> normalized bf16 wb (4 rows/block)
// blocks [8192, 8704): features -> normalized bf16 fb + fp32 tgt + rowsum=0
__global__ void prep_kernel(const float* __restrict__ feat,
                            const int* __restrict__ y,
                            const float* __restrict__ w,
                            __hip_bfloat16* __restrict__ fb,
                            __hip_bfloat16* __restrict__ wb,
                            float* __restrict__ tgt,
                            float* __restrict__ rowsum) {
  const int wave = threadIdx.x >> 6;
  const int l = threadIdx.x & 63;
  if (blockIdx.x < 8192) {
    const int row = blockIdx.x * 4 + wave;
    const floatx4* src = (const floatx4*)(w + (size_t)row * DK);
    floatx4 v0 = src[l];
    floatx4 v1 = src[64 + l];
    float s = dot4(v0, v0) + dot4(v1, v1);
#pragma unroll
    for (int off = 1; off < 64; off <<= 1) s += __shfl_xor(s, off, 64);
    const float scale = 1.0f / fmaxf(sqrtf(s), 1e-12f);
    v0 *= scale; v1 *= scale;
    uint2* db = (uint2*)(wb + (size_t)row * DK);
    db[l] = pack4(v0);
    db[64 + l] = pack4(v1);
  } else {
    const int i = (blockIdx.x - 8192) * 4 + wave;
    const floatx4* src = (const floatx4*)(feat + (size_t)i * DK);
    floatx4 v0 = src[l];
    floatx4 v1 = src[64 + l];
    const int cls = y[i];
    const floatx4* wr = (const floatx4*)(w + (size_t)cls * DK);
    floatx4 w0 = wr[l], w1 = wr[64 + l];
    float s  = dot4(v0, v0) + dot4(v1, v1);
    float d  = dot4(v0, w0) + dot4(v1, w1);
    float wn = dot4(w0, w0) + dot4(w1, w1);
#pragma unroll
    for (int off = 1; off < 64; off <<= 1) {
      s  += __shfl_xor(s, off, 64);
      d  += __shfl_xor(d, off, 64);
      wn += __shfl_xor(wn, off, 64);
    }
    const float fscale = 1.0f / fmaxf(sqrtf(s), 1e-12f);
    v0 *= fscale; v1 *= fscale;
    uint2* db = (uint2*)(fb + (size_t)i * DK);
    db[l] = pack4(v0);
    db[64 + l] = pack4(v1);
    if (l == 0) {
      tgt[i] = d * fscale / fmaxf(sqrtf(wn), 1e-12f);
      rowsum[i] = 0.0f;
    }
  }
}

// ---- kernel 2: 128(M)x256(N) bf16 MFMA GEMM + fused exp row-sum.
// Double-buffered LDS, one barrier per K-iter.
__launch_bounds__(512, 4)
__global__ void gemm_exp_kernel(const __hip_bfloat16* __restrict__ fb,   // [BN, DK]
                                const __hip_bfloat16* __restrict__ wb,   // [CN, DK]
                                float* __restrict__ rowsum) {
  __shared__ short As[2][128 * 32];   // 2 x  8 KB
  __shared__ short Bs[2][256 * 32];   // 2 x 16 KB
  __shared__ float lsum[128];

  const int tid  = threadIdx.x;
  const int wave = tid >> 6;
  const int lane = tid & 63;
  const int tileM = blockIdx.x * 128;
  const int tileN = blockIdx.y * 256;

  const int wm = (wave >> 2) * 64;  // wave M offset (0 or 64)
  const int wn = (wave & 3) * 64;   // wave N offset (0..192)

  if (tid < 128) lsum[tid] = 0.0f;  // covered by first K-loop barrier

  floatx4 acc[4][4];
#pragma unroll
  for (int mi = 0; mi < 4; ++mi)
#pragma unroll
    for (int ni = 0; ni < 4; ++ni)
      acc[mi][ni] = (floatx4){0.f, 0.f, 0.f, 0.f};

  // staging: 1536 16B chunks/iter (A:512, Blo:512, Bhi:512), 3 insts/thread.
  // chunk -> LDS row tid>>2, stored col tid&3; fetched global col XOR-swizzled.
  const int sr = tid >> 2;                 // 0..127
  const int sc = tid & 3;
  const int sg = sc ^ ((sr >> 1) & 3);
  const char* gA  = (const char*)fb + ((size_t)(tileM + sr)       * DK + sg * 8) * 2;
  const char* gB0 = (const char*)wb + ((size_t)(tileN + sr)       * DK + sg * 8) * 2;
  const char* gB1 = (const char*)wb + ((size_t)(tileN + 128 + sr) * DK + sg * 8) * 2;
  short* lA0  = &As[0][wave * 512];        // wave-uniform LDS bases
  short* lA1  = &As[1][wave * 512];
  short* lB00 = &Bs[0][wave * 512];
  short* lB01 = &Bs[0][4096 + wave * 512];
  short* lB10 = &Bs[1][wave * 512];
  short* lB11 = &Bs[1][4096 + wave * 512];

  const int mrow = lane & 15;   // fragment row (M or N index within 16)
  const int gk   = lane >> 4;   // logical k-chunk (16B) wanted by this lane

  // prologue: stage chunk 0 into buffer 0
  async_ld16(gA,  lA0);
  async_ld16(gB0, lB00);
  async_ld16(gB1, lB01);
  gA += 64; gB0 += 64; gB1 += 64;

#pragma unroll
  for (int kk = 0; kk < DK / 32; ++kk) {
    const int cur = kk & 1;
    // Barrier: (a) drains vmcnt -> buf[cur]'s loads (issued one full compute
    // phase ago) are resident; (b) all waves done reading buf[cur^1] (iter
    // kk-1), so it's safe to overwrite it below.
    __syncthreads();
    if (kk < DK / 32 - 1) {
      if (cur == 0) {
        async_ld16(gA,  lA1);
        async_ld16(gB0, lB10);
        async_ld16(gB1, lB11);
      } else {
        async_ld16(gA,  lA0);
        async_ld16(gB0, lB00);
        async_ld16(gB1, lB01);
      }
      gA += 64; gB0 += 64; gB1 += 64;
    }

    const short* Ab = As[cur];
    const short* Bb = Bs[cur];
    short8 af[4], bf[4];
#pragma unroll
    for (int mi = 0; mi < 4; ++mi) {
      const int row = wm + mi * 16 + mrow;
      const int c = gk ^ ((row >> 1) & 3);
      af[mi] = *(const short8*)&Ab[row * 32 + c * 8];
    }
#pragma unroll
    for (int ni = 0; ni < 4; ++ni) {
      const int row = wn + ni * 16 + mrow;
      const int c = gk ^ ((row >> 1) & 3);
      bf[ni] = *(const short8*)&Bb[row * 32 + c * 8];
    }
#pragma unroll
    for (int mi = 0; mi < 4; ++mi)
#pragma unroll
      for (int ni = 0; ni < 4; ++ni)
        acc[mi][ni] = __builtin_amdgcn_mfma_f32_16x16x32_bf16(
            af[mi], bf[ni], acc[mi][ni], 0, 0, 0);
  }

  // epilogue: rowsum[m] += sum_n exp(64 * wf[m][n])
  const int rowq = (lane >> 4) * 4;  // C/D layout: row = quad*4 + reg
#pragma unroll
  for (int mi = 0; mi < 4; ++mi) {
#pragma unroll
    for (int r = 0; r < 4; ++r) {
      float v = 0.f;
#pragma unroll
      for (int ni = 0; ni < 4; ++ni)
        v += __expf(64.0f * acc[mi][ni][r]);
      v += __shfl_xor(v, 1, 64);
      v += __shfl_xor(v, 2, 64);
      v += __shfl_xor(v, 4, 64);
      v += __shfl_xor(v, 8, 64);
      if ((lane & 15) == 0)
        atomicAdd(&lsum[wm + mi * 16 + rowq + r], v);
    }
  }
  __syncthreads();
  if (tid < 128)
    atomicAdd(&rowsum[tileM + tid], lsum[tid]);
}

// ---- kernel 3: final loss
__global__ void loss_kernel(const float* __restrict__ tgt,
                            const float* __restrict__ rowsum,
                            float* __restrict__ out) {
  __shared__ float wsum[8];
  const int t = threadIdx.x;
  float sum = 0.f;
  const float cM = 0.87758256189037271f;  // cos(0.5)
  const float sM = 0.47942553860420301f;  // sin(0.5)
  for (int i = t; i < BN; i += 512) {
    const float tg_raw = tgt[i];
    const float tg = fminf(fmaxf(tg_raw, -1.f + 1e-7f), 1.f - 1e-7f);
    const float num = 64.f * (tg * cM - sqrtf(fmaxf(1.f - tg * tg, 0.f)) * sM);
    const float den = expf(num) + rowsum[i] - expf(64.f * tg_raw);
    sum += num - logf(den);
  }
#pragma unroll
  for (int off = 1; off < 64; off <<= 1) sum += __shfl_xor(sum, off, 64);
  if ((t & 63) == 0) wsum[t >> 6] = sum;
  __syncthreads();
  if (t == 0) {
    float tot = 0.f;
#pragma unroll
    for (int k = 0; k < 8; ++k) tot += wsum[k];
    out[0] = -tot * (1.0f / (float)BN);
  }
}

extern "C" void kernel_launch(void* const* d_in, const int* in_sizes, int n_in,
                              void* d_out, int out_size, void* d_ws, size_t ws_size,
                              hipStream_t stream) {
  const float* features = (const float*)d_in[0];
  const int*   y_true   = (const int*)d_in[1];
  const float* weight   = (const float*)d_in[2];
  float* out = (float*)d_out;

  char* ws = (char*)d_ws;
  __hip_bfloat16* wb = (__hip_bfloat16*)(ws);             // 32 MB
  __hip_bfloat16* fb = (__hip_bfloat16*)(ws + 33554432);  //  2 MB
  float* tgt         = (float*)(ws + 35651584);           //  8 KB
  float* rowsum      = (float*)(ws + 35659776);           //  8 KB

  prep_kernel<<<8192 + 512, 256, 0, stream>>>(features, y_true, weight,
                                              fb, wb, tgt, rowsum);
  gemm_exp_kernel<<<dim3(BN / 128, CN / 256), 512, 0, stream>>>(fb, wb, rowsum);
  loss_kernel<<<1, 512, 0, stream>>>(tgt, rowsum, out);
}